// Round 1
// baseline (151.882 us; speedup 1.0000x reference)
//
#include <hip/hip_runtime.h>
#include <math.h>

#define HWPX 262144   // 512*512
#define NIMG 8
#define ACC_STRIDE 96
// accd layout per image (doubles):
// [0..15] cnt, [16..31] sum_x, [32..47] sum_y, [48..63] sum_sigma, [64..79] sum_sigma2,
// [80] bg_seed, [81] fit_seed, [82] inst_loss, [83] var_loss, [84] obj

template<bool PLANES>
__global__ __launch_bounds__(256) void k_prep(const float* __restrict__ pred,
    const int* __restrict__ inst, const int* __restrict__ lab,
    float* __restrict__ emx, float* __restrict__ emy, float* __restrict__ seedp,
    double* __restrict__ accd)
{
  __shared__ float s[81];
  int t = threadIdx.x;
  if (t < 81) s[t] = 0.0f;
  __syncthreads();
  int bid = blockIdx.x;
  int b = bid >> 7;                 // 128 blocks per image
  int base = (bid & 127) << 11;     // 2048 px per block
  const float* pb = pred + (size_t)b * 4 * HWPX;
  size_t ib = (size_t)b * HWPX;
  float bg = 0.0f;
  #pragma unroll
  for (int i = 0; i < 8; ++i) {
    int px = base + (i << 8) + t;
    int h = px >> 9, w = px & 511;
    float xm = w * (1.0f/1023.0f), ym = h * (1.0f/1023.0f);
    float sg = pb[2*HWPX + px];
    float p3 = pb[3*HWPX + px];
    float sd = 1.0f / (1.0f + __expf(-p3));
    if (PLANES) {
      emx[ib+px] = tanhf(pb[px]) + xm;
      emy[ib+px] = tanhf(pb[HWPX+px]) + ym;
      seedp[ib+px] = sd;
    }
    int lv = lab[ib+px], iv = inst[ib+px];
    if (lv == 0) {
      bg += sd*sd;
    } else if (lv == 1 && (unsigned)(iv-1) < 16u) {
      int k = iv - 1;
      atomicAdd(&s[k], 1.0f);
      atomicAdd(&s[16+k], xm);
      atomicAdd(&s[32+k], ym);
      atomicAdd(&s[48+k], sg);
      atomicAdd(&s[64+k], sg*sg);
    }
  }
  #pragma unroll
  for (int o = 32; o > 0; o >>= 1) bg += __shfl_down(bg, o);
  if ((t & 63) == 0) atomicAdd(&s[80], bg);
  __syncthreads();
  if (t < 81 && s[t] != 0.0f)
    atomicAdd(&accd[(size_t)b*ACC_STRIDE + t], (double)s[t]);
}

__global__ __launch_bounds__(128) void k_fin(double* __restrict__ accd, float* __restrict__ pairinfo)
{
  __shared__ double varr[128];
  __shared__ float pres[128];
  int t = threadIdx.x;
  int b = t >> 4, k = t & 15;
  double* ab = accd + (size_t)b*ACC_STRIDE;
  double cnt = ab[k];
  double safe = cnt > 0.0 ? cnt : 1.0;
  double ss = ab[48+k];
  double cx = ab[16+k]/safe, cy = ab[32+k]/safe, sm = ss/safe;
  double var = (ab[64+k] - ss*ss/safe)/safe;   // sum (sigma - mean)^2 / safe
  if (var < 0.0) var = 0.0;
  float4 pi = make_float4((float)cx, (float)cy, (float)exp(10.0*sm), (float)cnt);
  reinterpret_cast<float4*>(pairinfo)[t] = pi;
  pres[t] = cnt > 0.0 ? 1.0f : 0.0f;
  varr[t] = cnt > 0.0 ? var : 0.0;
  __syncthreads();
  if (t < NIMG) {
    float np = 0.0f; double vs = 0.0;
    for (int i = 0; i < 16; ++i) { np += pres[t*16+i]; vs += varr[t*16+i]; }
    double* ab2 = accd + (size_t)t*ACC_STRIDE;
    ab2[83] = vs;
    ab2[84] = (np > 1.0f) ? (double)np : 1.0;
  }
}

// One block per (image, instance). Builds an LDS histogram of hinge errors keyed by
// float bits >> SHIFT (monotone for e>=0), then does an in-block descending scan to
// evaluate the Lovasz integral  sum_bins val * (J_after - J_before),  J = i/(G+N).
template<bool PLANES, int SHIFT>
__global__ __launch_bounds__(1024) void k_lov(const float* __restrict__ pred,
    const float* __restrict__ emx, const float* __restrict__ emy, const float* __restrict__ seedp,
    const int* __restrict__ inst, const int* __restrict__ lab,
    const float* __restrict__ pairinfo, double* __restrict__ accd)
{
  constexpr int NBB = (0x40000000 >> SHIFT) + 1;
  extern __shared__ unsigned char smem[];
  unsigned* histP = reinterpret_cast<unsigned*>(smem);
  unsigned* histQ = histP + NBB;
  unsigned* scanP = histQ + NBB;
  unsigned* scanQ = scanP + 1024;
  float* red  = reinterpret_cast<float*>(scanQ + 1024);  // [16]
  float* redf = red + 16;                                 // [16]
  int t = threadIdx.x, bid = blockIdx.x;
  int b = bid >> 4, k = bid & 15;
  float4 pi = reinterpret_cast<const float4*>(pairinfo)[bid];
  float cx = pi.x, cy = pi.y, sexp = pi.z, G = pi.w;
  if (G <= 0.0f) return;   // absent instance: contributes nothing (uniform exit)
  for (int i = t; i < 2*NBB; i += 1024) histP[i] = 0u;   // histP+histQ contiguous
  __syncthreads();
  size_t ib = (size_t)b * HWPX;
  const float* pb = pred + (size_t)b * 4 * HWPX;
  const int target = k + 1;
  float fit = 0.0f;
  for (int j = 0; j < HWPX/1024; ++j) {
    int px = (j << 10) + t;
    float ex, ey, sd;
    if (PLANES) {
      ex = emx[ib+px]; ey = emy[ib+px]; sd = seedp[ib+px];
    } else {
      int h = px >> 9, w = px & 511;
      ex = tanhf(pb[px]) + w*(1.0f/1023.0f);
      ey = tanhf(pb[HWPX+px]) + h*(1.0f/1023.0f);
      sd = 1.0f/(1.0f + __expf(-pb[3*HWPX+px]));
    }
    int lv = lab[ib+px], iv = inst[ib+px];
    float dx = ex - cx, dy = ey - cy;
    float d = __expf(-sexp * (dx*dx + dy*dy));
    bool m = (lv == 1) && (iv == target);
    float e = m ? fmaf(-2.0f, d, 2.0f) : 2.0f * d;   // hinge error, always >= 0
    unsigned key = __float_as_uint(e) >> SHIFT;
    atomicAdd(m ? &histP[key] : &histQ[key], 1u);
    if (m) { float df = sd - d; fit += df*df; }
  }
  #pragma unroll
  for (int o = 32; o > 0; o >>= 1) fit += __shfl_down(fit, o);
  if ((t & 63) == 0) redf[t >> 6] = fit;
  __syncthreads();

  // descending-key scan: thread t owns keys [start .. start-nk+1]
  constexpr int CB = NBB / 1024;
  int start = (NBB - 1) - t * CB;
  int nk = (t == 1023) ? (CB + 1) : CB;   // last thread also covers key 0
  unsigned lp = 0, lq = 0;
  for (int i = 0; i < nk; ++i) { lp += histP[start-i]; lq += histQ[start-i]; }
  scanP[t] = lp; scanQ[t] = lq;
  __syncthreads();
  for (int off = 1; off < 1024; off <<= 1) {
    unsigned vp = 0, vq = 0;
    if (t >= off) { vp = scanP[t-off]; vq = scanQ[t-off]; }
    __syncthreads();
    scanP[t] += vp; scanQ[t] += vq;
    __syncthreads();
  }
  float A  = (float)(scanP[t] - lp);   // positives strictly above my chunk
  float Bn = (float)(scanQ[t] - lq);   // negatives strictly above my chunk
  float contrib = 0.0f;
  for (int i = 0; i < nk; ++i) {
    int kk = start - i;
    unsigned p = histP[kk], q = histQ[kk];
    if (p | q) {
      float lo = __uint_as_float((unsigned)kk << SHIFT);
      float hi = __uint_as_float((unsigned)(kk+1) << SHIFT);
      float val = 0.5f*(lo+hi);
      if (val > 2.0f) val = 2.0f;
      float pq = (float)(p + q), qf = (float)q;
      float Jb = (A + Bn) / (G + Bn);
      float Ja = (A + Bn + pq) / (G + Bn + qf);
      contrib += val * (Ja - Jb);
      A += (float)p; Bn += qf;
    }
  }
  #pragma unroll
  for (int o = 32; o > 0; o >>= 1) contrib += __shfl_down(contrib, o);
  if ((t & 63) == 0) red[t >> 6] = contrib;
  __syncthreads();
  if (t == 0) {
    float tot = 0.0f, ft = 0.0f;
    for (int i = 0; i < 16; ++i) { tot += red[i]; ft += redf[i]; }
    atomicAdd(&accd[(size_t)b*ACC_STRIDE + 82], (double)tot);
    atomicAdd(&accd[(size_t)b*ACC_STRIDE + 81], (double)ft);
  }
}

__global__ void k_final(const double* __restrict__ accd, float* __restrict__ out)
{
  int t = threadIdx.x;
  double lb = 0.0;
  if (t < NIMG) {
    const double* ab = accd + (size_t)t*ACC_STRIDE;
    lb = (ab[82] + 10.0*ab[83]) / ab[84] + (ab[80] + ab[81]) * (1.0/(double)HWPX);
  }
  #pragma unroll
  for (int o = 4; o > 0; o >>= 1) lb += __shfl_down(lb, o);
  if (t == 0) out[0] = (float)(lb * 0.125);
}

extern "C" void kernel_launch(void* const* d_in, const int* in_sizes, int n_in,
                              void* d_out, int out_size, void* d_ws, size_t ws_size,
                              hipStream_t stream)
{
  const float* pred = (const float*)d_in[0];
  const int*   inst = (const int*)d_in[1];
  const int*   lab  = (const int*)d_in[2];
  float* out = (float*)d_out;

  size_t planesBytes = (size_t)3 * NIMG * HWPX * sizeof(float);
  size_t accBytes  = (size_t)NIMG * ACC_STRIDE * sizeof(double);
  size_t pairBytes = 128 * 4 * sizeof(float);
  bool planes = ws_size >= planesBytes + accBytes + pairBytes;

  char* ws = (char*)d_ws;
  float *emx = nullptr, *emy = nullptr, *seedp = nullptr;
  double* accd;
  if (planes) {
    emx = (float*)ws;
    emy = emx + (size_t)NIMG*HWPX;
    seedp = emy + (size_t)NIMG*HWPX;
    accd = (double*)(seedp + (size_t)NIMG*HWPX);
  } else {
    accd = (double*)ws;
  }
  float* pairinfo = (float*)(accd + NIMG*ACC_STRIDE);

  hipMemsetAsync(accd, 0, accBytes, stream);
  if (planes) k_prep<true ><<<1024,256,0,stream>>>(pred, inst, lab, emx, emy, seedp, accd);
  else        k_prep<false><<<1024,256,0,stream>>>(pred, inst, lab, emx, emy, seedp, accd);
  k_fin<<<1,128,0,stream>>>(accd, pairinfo);

  size_t lds17 = ((size_t)2*8193 + 2048)*4 + 128;   // 73864 B -> needs attribute (>64KB)
  size_t lds18 = ((size_t)2*4097 + 2048)*4 + 128;   // 41096 B -> fine by default
  if (planes) {
    if (hipFuncSetAttribute(reinterpret_cast<const void*>(&k_lov<true,17>),
          hipFuncAttributeMaxDynamicSharedMemorySize, (int)lds17) == hipSuccess)
      k_lov<true,17><<<128,1024,lds17,stream>>>(pred, emx, emy, seedp, inst, lab, pairinfo, accd);
    else
      k_lov<true,18><<<128,1024,lds18,stream>>>(pred, emx, emy, seedp, inst, lab, pairinfo, accd);
  } else {
    if (hipFuncSetAttribute(reinterpret_cast<const void*>(&k_lov<false,17>),
          hipFuncAttributeMaxDynamicSharedMemorySize, (int)lds17) == hipSuccess)
      k_lov<false,17><<<128,1024,lds17,stream>>>(pred, emx, emy, seedp, inst, lab, pairinfo, accd);
    else
      k_lov<false,18><<<128,1024,lds18,stream>>>(pred, emx, emy, seedp, inst, lab, pairinfo, accd);
  }
  k_final<<<1,64,0,stream>>>(accd, out);
}

// Round 2
// 73.738 us; speedup vs baseline: 2.0598x; 2.0598x over previous
//
#include <hip/hip_runtime.h>
#include <hip/hip_fp16.h>
#include <math.h>

#define HWPX 262144   // 512*512
#define NIMG 8
#define ACC_STRIDE 96
#define NB 1024       // linear histogram bins over e in [0,2]
#define NSPLIT 32
#define NGRP 2
// accd layout per image (doubles):
// [0..15] cnt, [16..31] sum_x, [32..47] sum_y, [48..63] sum_sigma, [64..79] sum_sigma2,
// [80] bg_seed, [81] fit_seed, [82] inst_loss, [83] var_loss, [84] obj

// ---------- stats (+ optional packed-record write) ----------
template<bool PACK>
__global__ __launch_bounds__(256) void k_prep(const float* __restrict__ pred,
    const int* __restrict__ inst, const int* __restrict__ lab,
    float2* __restrict__ exy, unsigned* __restrict__ meta, double* __restrict__ accd)
{
  __shared__ float s[81];
  int t = threadIdx.x;
  if (t < 81) s[t] = 0.0f;
  __syncthreads();
  int bid = blockIdx.x;
  int b = bid >> 7;                 // 128 blocks per image
  int base = (bid & 127) << 11;     // 2048 px per block
  const float* pb = pred + (size_t)b * 4 * HWPX;
  size_t ib = (size_t)b * HWPX;
  float bg = 0.0f;
  #pragma unroll
  for (int i = 0; i < 8; ++i) {
    int px = base + (i << 8) + t;
    int h = px >> 9, w = px & 511;
    float xm = w * (1.0f/1023.0f), ym = h * (1.0f/1023.0f);
    float sg = pb[2*HWPX + px];
    float p3 = pb[3*HWPX + px];
    float sd = 1.0f / (1.0f + __expf(-p3));
    int lv = lab[ib+px], iv = inst[ib+px];
    int mid = (lv == 1 && (unsigned)(iv-1) < 16u) ? iv : 0;
    if (PACK) {
      float ex = tanhf(pb[px]) + xm;
      float ey = tanhf(pb[HWPX+px]) + ym;
      exy[ib+px] = make_float2(ex, ey);
      unsigned hs = (unsigned)__half_as_ushort(__float2half(sd));
      meta[ib+px] = (hs << 16) | (unsigned)mid;
    }
    if (lv == 0) {
      bg += sd*sd;
    } else if (mid) {
      int k = mid - 1;
      atomicAdd(&s[k], 1.0f);
      atomicAdd(&s[16+k], xm);
      atomicAdd(&s[32+k], ym);
      atomicAdd(&s[48+k], sg);
      atomicAdd(&s[64+k], sg*sg);
    }
  }
  #pragma unroll
  for (int o = 32; o > 0; o >>= 1) bg += __shfl_down(bg, o);
  if ((t & 63) == 0) atomicAdd(&s[80], bg);
  __syncthreads();
  if (t < 81 && s[t] != 0.0f)
    atomicAdd(&accd[(size_t)b*ACC_STRIDE + t], (double)s[t]);
}

__global__ __launch_bounds__(128) void k_fin(double* __restrict__ accd, float* __restrict__ pairinfo)
{
  __shared__ double varr[128];
  __shared__ float pres[128];
  int t = threadIdx.x;
  int b = t >> 4, k = t & 15;
  double* ab = accd + (size_t)b*ACC_STRIDE;
  double cnt = ab[k];
  double safe = cnt > 0.0 ? cnt : 1.0;
  double ss = ab[48+k];
  double cx = ab[16+k]/safe, cy = ab[32+k]/safe, sm = ss/safe;
  double var = (ab[64+k] - ss*ss/safe)/safe;
  if (var < 0.0) var = 0.0;
  float4 pi = make_float4((float)cx, (float)cy, (float)exp(10.0*sm), (float)cnt);
  reinterpret_cast<float4*>(pairinfo)[t] = pi;
  pres[t] = cnt > 0.0 ? 1.0f : 0.0f;
  varr[t] = cnt > 0.0 ? var : 0.0;
  __syncthreads();
  if (t < NIMG) {
    float np = 0.0f; double vs = 0.0;
    for (int i = 0; i < 16; ++i) { np += pres[t*16+i]; vs += varr[t*16+i]; }
    double* ab2 = accd + (size_t)t*ACC_STRIDE;
    ab2[83] = vs;
    ab2[84] = (np > 1.0f) ? (double)np : 1.0;
  }
}

// ---------- tier1: histogram (8 instances per block, 32 pixel-splits) ----------
__global__ __launch_bounds__(1024) void k_hist(const float2* __restrict__ exy,
    const unsigned* __restrict__ meta, const float* __restrict__ pairinfo,
    unsigned* __restrict__ partial, double* __restrict__ accd)
{
  __shared__ unsigned hist[8*NB];   // 32 KB, P in high 16, Q in low 16
  __shared__ float redf[16];
  int t = threadIdx.x, bid = blockIdx.x;
  int b = bid & 7;                  // XCD-local image
  int r = bid >> 3;
  int g = r & 1;                    // instance group (0: ids 1..8, 1: ids 9..16)
  int s = r >> 1;                   // pixel split 0..31
  for (int i = t; i < 8*NB; i += 1024) hist[i] = 0u;
  float4 pi[8];
  #pragma unroll
  for (int j = 0; j < 8; ++j)
    pi[j] = reinterpret_cast<const float4*>(pairinfo)[b*16 + g*8 + j];
  __syncthreads();
  size_t base = (size_t)b*HWPX + (size_t)s*(HWPX/NSPLIT);
  float fit = 0.0f;
  for (int it = 0; it < HWPX/NSPLIT/1024; ++it) {   // 8 iterations
    size_t px = base + it*1024 + t;
    float2 e2 = exy[px];
    unsigned mv = meta[px];
    int mid = (int)(mv & 0xffu);
    float sd = __half2float(__ushort_as_half((unsigned short)(mv >> 16)));
    #pragma unroll
    for (int j = 0; j < 8; ++j) {
      float dx = e2.x - pi[j].x, dy = e2.y - pi[j].y;
      float d = __expf(-pi[j].z * (dx*dx + dy*dy));
      bool m = (mid == g*8 + j + 1);
      float e = m ? fmaf(-2.0f, d, 2.0f) : 2.0f*d;
      int key = (int)(e * (float)(NB/2));
      if (key > NB-1) key = NB-1;
      atomicAdd(&hist[j*NB + key], m ? 0x10000u : 1u);
      if (m) { float df = sd - d; fit += df*df; }
    }
  }
  #pragma unroll
  for (int o = 32; o > 0; o >>= 1) fit += __shfl_down(fit, o);
  if ((t & 63) == 0) redf[t >> 6] = fit;
  __syncthreads();
  if (t == 0) {
    float ft = 0.0f;
    for (int i = 0; i < 16; ++i) ft += redf[i];
    atomicAdd(&accd[(size_t)b*ACC_STRIDE + 81], (double)ft);
  }
  unsigned* pp = partial + (size_t)((b*NGRP + g)*NSPLIT + s)*(8*NB);
  for (int i = t; i < 8*NB; i += 1024) pp[i] = hist[i];
}

// ---------- tier1: merge partials + descending scan + Lovasz integral ----------
__global__ __launch_bounds__(1024) void k_scan(const unsigned* __restrict__ partial,
    const float* __restrict__ pairinfo, double* __restrict__ accd)
{
  __shared__ unsigned sp[NB], sq[NB];
  __shared__ float red[16];
  int t = threadIdx.x, bid = blockIdx.x;
  int b = bid >> 4, k = bid & 15;
  int g = k >> 3, j8 = k & 7;
  float G = pairinfo[(b*16 + k)*4 + 3];
  if (G <= 0.0f) return;   // absent instance (uniform block exit)
  unsigned p = 0, q = 0;
  const unsigned* basep = partial + (size_t)((b*NGRP + g)*NSPLIT)*(8*NB) + j8*NB + t;
  #pragma unroll 4
  for (int s2 = 0; s2 < NSPLIT; ++s2) {
    unsigned h = basep[(size_t)s2*(8*NB)];
    p += h >> 16; q += h & 0xffffu;
  }
  int j = (NB-1) - t;          // descending rank: j=0 is the largest-error bin
  sp[j] = p; sq[j] = q;
  __syncthreads();
  for (int off = 1; off < NB; off <<= 1) {
    unsigned vp = 0, vq = 0;
    if (j >= off) { vp = sp[j-off]; vq = sq[j-off]; }
    __syncthreads();
    sp[j] += vp; sq[j] += vq;
    __syncthreads();
  }
  float A  = (float)(sp[j] - p);   // positives strictly above my bin
  float Bn = (float)(sq[j] - q);   // negatives strictly above my bin
  float val = (t + 0.5f) * (2.0f/NB);
  float pf = (float)p, qf = (float)q;
  float Jb = (A + Bn) / (G + Bn);
  float Ja = (A + Bn + pf + qf) / (G + Bn + qf);
  float contrib = val * (Ja - Jb);
  #pragma unroll
  for (int o = 32; o > 0; o >>= 1) contrib += __shfl_down(contrib, o);
  if ((t & 63) == 0) red[t >> 6] = contrib;
  __syncthreads();
  if (t == 0) {
    float tot = 0.0f;
    for (int i = 0; i < 16; ++i) tot += red[i];
    atomicAdd(&accd[(size_t)b*ACC_STRIDE + 82], (double)tot);
  }
}

// ---------- tier3 fallback: proven round-1 kernel (recompute path, SHIFT=18) ----------
__global__ __launch_bounds__(1024) void k_lov_old(const float* __restrict__ pred,
    const int* __restrict__ inst, const int* __restrict__ lab,
    const float* __restrict__ pairinfo, double* __restrict__ accd)
{
  constexpr int SHIFT = 18;
  constexpr int NBB = (0x40000000 >> SHIFT) + 1;
  extern __shared__ unsigned char smem[];
  unsigned* histP = reinterpret_cast<unsigned*>(smem);
  unsigned* histQ = histP + NBB;
  unsigned* scanP = histQ + NBB;
  unsigned* scanQ = scanP + 1024;
  float* red  = reinterpret_cast<float*>(scanQ + 1024);
  float* redf = red + 16;
  int t = threadIdx.x, bid = blockIdx.x;
  int b = bid >> 4, k = bid & 15;
  float4 pi = reinterpret_cast<const float4*>(pairinfo)[bid];
  float cx = pi.x, cy = pi.y, sexp = pi.z, G = pi.w;
  if (G <= 0.0f) return;
  for (int i = t; i < 2*NBB; i += 1024) histP[i] = 0u;
  __syncthreads();
  size_t ib = (size_t)b * HWPX;
  const float* pb = pred + (size_t)b * 4 * HWPX;
  const int target = k + 1;
  float fit = 0.0f;
  for (int j = 0; j < HWPX/1024; ++j) {
    int px = (j << 10) + t;
    int h = px >> 9, w = px & 511;
    float ex = tanhf(pb[px]) + w*(1.0f/1023.0f);
    float ey = tanhf(pb[HWPX+px]) + h*(1.0f/1023.0f);
    float sd = 1.0f/(1.0f + __expf(-pb[3*HWPX+px]));
    int lv = lab[ib+px], iv = inst[ib+px];
    float dx = ex - cx, dy = ey - cy;
    float d = __expf(-sexp * (dx*dx + dy*dy));
    bool m = (lv == 1) && (iv == target);
    float e = m ? fmaf(-2.0f, d, 2.0f) : 2.0f * d;
    unsigned key = __float_as_uint(e) >> SHIFT;
    atomicAdd(m ? &histP[key] : &histQ[key], 1u);
    if (m) { float df = sd - d; fit += df*df; }
  }
  #pragma unroll
  for (int o = 32; o > 0; o >>= 1) fit += __shfl_down(fit, o);
  if ((t & 63) == 0) redf[t >> 6] = fit;
  __syncthreads();
  constexpr int CB = NBB / 1024;
  int start = (NBB - 1) - t * CB;
  int nk = (t == 1023) ? (CB + 1) : CB;
  unsigned lp = 0, lq = 0;
  for (int i = 0; i < nk; ++i) { lp += histP[start-i]; lq += histQ[start-i]; }
  scanP[t] = lp; scanQ[t] = lq;
  __syncthreads();
  for (int off = 1; off < 1024; off <<= 1) {
    unsigned vp = 0, vq = 0;
    if (t >= off) { vp = scanP[t-off]; vq = scanQ[t-off]; }
    __syncthreads();
    scanP[t] += vp; scanQ[t] += vq;
    __syncthreads();
  }
  float A  = (float)(scanP[t] - lp);
  float Bn = (float)(scanQ[t] - lq);
  float contrib = 0.0f;
  for (int i = 0; i < nk; ++i) {
    int kk = start - i;
    unsigned p = histP[kk], q = histQ[kk];
    if (p | q) {
      float lo = __uint_as_float((unsigned)kk << SHIFT);
      float hi = __uint_as_float((unsigned)(kk+1) << SHIFT);
      float valv = 0.5f*(lo+hi);
      if (valv > 2.0f) valv = 2.0f;
      float pq = (float)(p + q), qf = (float)q;
      float Jb = (A + Bn) / (G + Bn);
      float Ja = (A + Bn + pq) / (G + Bn + qf);
      contrib += valv * (Ja - Jb);
      A += (float)p; Bn += qf;
    }
  }
  #pragma unroll
  for (int o = 32; o > 0; o >>= 1) contrib += __shfl_down(contrib, o);
  if ((t & 63) == 0) red[t >> 6] = contrib;
  __syncthreads();
  if (t == 0) {
    float tot = 0.0f, ft = 0.0f;
    for (int i = 0; i < 16; ++i) { tot += red[i]; ft += redf[i]; }
    atomicAdd(&accd[(size_t)b*ACC_STRIDE + 82], (double)tot);
    atomicAdd(&accd[(size_t)b*ACC_STRIDE + 81], (double)ft);
  }
}

__global__ void k_final(const double* __restrict__ accd, float* __restrict__ out)
{
  int t = threadIdx.x;
  double lb = 0.0;
  if (t < NIMG) {
    const double* ab = accd + (size_t)t*ACC_STRIDE;
    lb = (ab[82] + 10.0*ab[83]) / ab[84] + (ab[80] + ab[81]) * (1.0/(double)HWPX);
  }
  #pragma unroll
  for (int o = 4; o > 0; o >>= 1) lb += __shfl_down(lb, o);
  if (t == 0) out[0] = (float)(lb * 0.125);
}

extern "C" void kernel_launch(void* const* d_in, const int* in_sizes, int n_in,
                              void* d_out, int out_size, void* d_ws, size_t ws_size,
                              hipStream_t stream)
{
  const float* pred = (const float*)d_in[0];
  const int*   inst = (const int*)d_in[1];
  const int*   lab  = (const int*)d_in[2];
  float* out = (float*)d_out;

  size_t exyB  = (size_t)NIMG * HWPX * sizeof(float2);      // 16.78 MB
  size_t metaB = (size_t)NIMG * HWPX * sizeof(unsigned);    //  8.39 MB
  size_t partB = (size_t)NIMG * NGRP * NSPLIT * 8 * NB * 4; // 16.78 MB
  size_t accB  = (size_t)NIMG * ACC_STRIDE * sizeof(double);
  size_t pairB = 128 * 4 * sizeof(float);
  bool full = ws_size >= exyB + metaB + partB + accB + pairB;

  char* ws = (char*)d_ws;
  if (full) {
    float2*   exy   = (float2*)ws;
    unsigned* meta  = (unsigned*)(ws + exyB);
    unsigned* part  = (unsigned*)(ws + exyB + metaB);
    double*   accd  = (double*)(ws + exyB + metaB + partB);
    float*    pairinfo = (float*)(ws + exyB + metaB + partB + accB);
    hipMemsetAsync(accd, 0, accB, stream);
    k_prep<true><<<1024,256,0,stream>>>(pred, inst, lab, exy, meta, accd);
    k_fin<<<1,128,0,stream>>>(accd, pairinfo);
    k_hist<<<NIMG*NGRP*NSPLIT,1024,0,stream>>>(exy, meta, pairinfo, part, accd);
    k_scan<<<128,1024,0,stream>>>(part, pairinfo, accd);
    k_final<<<1,64,0,stream>>>(accd, out);
  } else {
    double* accd = (double*)ws;
    float* pairinfo = (float*)(accd + NIMG*ACC_STRIDE);
    hipMemsetAsync(accd, 0, accB, stream);
    k_prep<false><<<1024,256,0,stream>>>(pred, inst, lab, nullptr, nullptr, accd);
    k_fin<<<1,128,0,stream>>>(accd, pairinfo);
    size_t lds18 = ((size_t)2*4097 + 2048)*4 + 128;
    k_lov_old<<<128,1024,lds18,stream>>>(pred, inst, lab, pairinfo, accd);
    k_final<<<1,64,0,stream>>>(accd, out);
  }
}

// Round 3
// 72.835 us; speedup vs baseline: 2.0853x; 1.0124x over previous
//
#include <hip/hip_runtime.h>
#include <hip/hip_fp16.h>
#include <math.h>

#define HWPX 262144   // 512*512
#define NIMG 8
#define ACC_STRIDE 96
#define NB 1024       // histogram bins (e-space for P, z-space for Q)
#define ZMAX 8.0f
#define NSPLIT 32
#define NGRP 2
// accd layout per image (doubles):
// [0..15] cnt, [16..31] sum_x, [32..47] sum_y, [48..63] sum_sigma, [64..79] sum_sigma2,
// [80] bg_seed, [81] fit_seed, [82] inst_loss, [83] var_loss, [84] obj

typedef unsigned long long u64;

// ---------- stats (+ optional packed-record write), 8-replica LDS accumulators ----------
template<bool PACK>
__global__ __launch_bounds__(256) void k_prep(const float* __restrict__ pred,
    const int* __restrict__ inst, const int* __restrict__ lab,
    u64* __restrict__ rec, double* __restrict__ accd)
{
  __shared__ float s[8][83];   // stride 83: coprime with 32 banks
  int t = threadIdx.x;
  for (int i = t; i < 8*83; i += 256) (&s[0][0])[i] = 0.0f;
  __syncthreads();
  int bid = blockIdx.x;
  int b = bid >> 7;                 // 128 blocks per image
  int base = (bid & 127) << 11;     // 2048 px per block
  const float* pb = pred + (size_t)b * 4 * HWPX;
  size_t ib = (size_t)b * HWPX;
  int r = t & 7;
  float bg = 0.0f;
  #pragma unroll
  for (int i = 0; i < 8; ++i) {
    int px = base + (i << 8) + t;
    int h = px >> 9, w = px & 511;
    float xm = w * (1.0f/1023.0f), ym = h * (1.0f/1023.0f);
    float sg = pb[2*HWPX + px];
    float p3 = pb[3*HWPX + px];
    float sd = 1.0f / (1.0f + __expf(-p3));
    int lv = lab[ib+px], iv = inst[ib+px];
    int mid = (lv == 1 && (unsigned)(iv-1) < 16u) ? iv : 0;
    if (PACK) {
      float ex = tanhf(pb[px]) + xm;
      float ey = tanhf(pb[HWPX+px]) + ym;
      u64 v = (u64)__half_as_ushort(__float2half(ex))
            | ((u64)__half_as_ushort(__float2half(ey)) << 16)
            | ((u64)__half_as_ushort(__float2half(sd)) << 32)
            | ((u64)mid << 48);
      rec[ib+px] = v;
    }
    if (lv == 0) {
      bg += sd*sd;
    } else if (mid) {
      int k = mid - 1;
      atomicAdd(&s[r][k], 1.0f);
      atomicAdd(&s[r][16+k], xm);
      atomicAdd(&s[r][32+k], ym);
      atomicAdd(&s[r][48+k], sg);
      atomicAdd(&s[r][64+k], sg*sg);
    }
  }
  #pragma unroll
  for (int o = 32; o > 0; o >>= 1) bg += __shfl_down(bg, o);
  if ((t & 63) == 0) atomicAdd(&s[0][80], bg);
  __syncthreads();
  if (t < 81) {
    float v = 0.0f;
    #pragma unroll
    for (int rr = 0; rr < 8; ++rr) v += s[rr][t];
    if (v != 0.0f) atomicAdd(&accd[(size_t)b*ACC_STRIDE + t], (double)v);
  }
}

__global__ __launch_bounds__(128) void k_fin(double* __restrict__ accd, float* __restrict__ pairinfo)
{
  __shared__ double varr[128];
  __shared__ float pres[128];
  int t = threadIdx.x;
  int b = t >> 4, k = t & 15;
  double* ab = accd + (size_t)b*ACC_STRIDE;
  double cnt = ab[k];
  double safe = cnt > 0.0 ? cnt : 1.0;
  double ss = ab[48+k];
  double cx = ab[16+k]/safe, cy = ab[32+k]/safe, sm = ss/safe;
  double var = (ab[64+k] - ss*ss/safe)/safe;
  if (var < 0.0) var = 0.0;
  float4 pi = make_float4((float)cx, (float)cy, (float)exp(10.0*sm), (float)cnt);
  reinterpret_cast<float4*>(pairinfo)[t] = pi;
  pres[t] = cnt > 0.0 ? 1.0f : 0.0f;
  varr[t] = cnt > 0.0 ? var : 0.0;
  __syncthreads();
  if (t < NIMG) {
    float np = 0.0f; double vs = 0.0;
    for (int i = 0; i < 16; ++i) { np += pres[t*16+i]; vs += varr[t*16+i]; }
    double* ab2 = accd + (size_t)t*ACC_STRIDE;
    ab2[83] = vs;
    ab2[84] = (np > 1.0f) ? (double)np : 1.0;
  }
}

// ---------- tier1: histogram (8 instances/block, z-binned negatives: no exp) ----------
__global__ __launch_bounds__(1024) void k_hist(const u64* __restrict__ rec,
    const float* __restrict__ pairinfo,
    unsigned* __restrict__ partial, double* __restrict__ accd)
{
  __shared__ unsigned hist[8*NB];   // 32 KB, P<<16 at e-bin, Q at z-bin
  __shared__ float redf[16];
  int t = threadIdx.x, bid = blockIdx.x;
  int b = bid & 7;                  // XCD-local image
  int r = bid >> 3;
  int g = r & 1;                    // instance group
  int s = r >> 1;                   // pixel split 0..31
  for (int i = t; i < 8*NB; i += 1024) hist[i] = 0u;
  float cx[8], cy[8], se[8], s128[8];
  #pragma unroll
  for (int j = 0; j < 8; ++j) {
    float4 pi = reinterpret_cast<const float4*>(pairinfo)[b*16 + g*8 + j];
    cx[j] = pi.x; cy[j] = pi.y; se[j] = pi.z; s128[j] = pi.z * (float)(NB/ZMAX);
  }
  __syncthreads();
  size_t base = (size_t)b*HWPX + (size_t)s*(HWPX/NSPLIT);
  float fit = 0.0f;
  for (int it = 0; it < HWPX/NSPLIT/1024; ++it) {   // 8 iterations
    size_t px = base + it*1024 + t;
    u64 v = rec[px];
    float ex = __half2float(__ushort_as_half((unsigned short)(v & 0xffffu)));
    float ey = __half2float(__ushort_as_half((unsigned short)((v >> 16) & 0xffffu)));
    float sd = __half2float(__ushort_as_half((unsigned short)((v >> 32) & 0xffffu)));
    int rel = (int)(v >> 48) - 1 - g*8;   // 0..7 iff this pixel's instance is in group
    #pragma unroll
    for (int j = 0; j < 8; ++j) {
      float dx = ex - cx[j], dy = ey - cy[j];
      float d2 = fmaf(dx, dx, dy*dy);
      int key; unsigned add;
      if (rel == j) {                       // positive (rare)
        float d = __expf(-d2 * se[j]);
        float e = fmaf(-2.0f, d, 2.0f);
        int kk = (int)(e * (float)(NB/2));
        key = kk > NB-1 ? NB-1 : kk;
        add = 0x10000u;
        float df = sd - d; fit += df*df;
      } else {                              // negative: z-bin, no exp
        key = (int)fminf(d2 * s128[j], (float)(NB-1));
        add = 1u;
      }
      atomicAdd(&hist[j*NB + key], add);
    }
  }
  #pragma unroll
  for (int o = 32; o > 0; o >>= 1) fit += __shfl_down(fit, o);
  if ((t & 63) == 0) redf[t >> 6] = fit;
  __syncthreads();
  if (t == 0) {
    float ft = 0.0f;
    for (int i = 0; i < 16; ++i) ft += redf[i];
    atomicAdd(&accd[(size_t)b*ACC_STRIDE + 81], (double)ft);
  }
  unsigned* pp = partial + (size_t)((b*NGRP + g)*NSPLIT + s)*(8*NB);
  for (int i = t; i < 8*NB; i += 1024) pp[i] = hist[i];
}

// ---------- tier1: merge partials, Q z->e conversion, descending scan + integral ----------
__global__ __launch_bounds__(1024) void k_scan(const unsigned* __restrict__ partial,
    const float* __restrict__ pairinfo, double* __restrict__ accd)
{
  __shared__ unsigned sp[NB], sq[NB];
  __shared__ float red[16];
  int t = threadIdx.x, bid = blockIdx.x;
  int b = bid >> 4, k = bid & 15;
  int g = k >> 3, j8 = k & 7;
  float G = pairinfo[(b*16 + k)*4 + 3];
  if (G <= 0.0f) return;   // absent instance (uniform block exit)
  sq[t] = 0u;
  __syncthreads();
  unsigned p = 0, q = 0;
  const unsigned* basep = partial + (size_t)((b*NGRP + g)*NSPLIT)*(8*NB) + j8*NB + t;
  #pragma unroll 4
  for (int s2 = 0; s2 < NSPLIT; ++s2) {
    unsigned h = basep[(size_t)s2*(8*NB)];
    p += h >> 16; q += h & 0xffffu;
  }
  // q is a z-bin count: convert to e-bin (e = 2*exp(-z_mid))
  float zmid = (t + 0.5f) * (ZMAX/NB);
  float ev = 2.0f * __expf(-zmid);
  int eb = (int)(ev * (float)(NB/2));
  if (eb > NB-1) eb = NB-1;
  if (q) atomicAdd(&sq[eb], q);
  __syncthreads();
  unsigned qe = sq[t];
  __syncthreads();
  int j = (NB-1) - t;          // descending-e rank
  sp[j] = p; sq[j] = qe;
  __syncthreads();
  for (int off = 1; off < NB; off <<= 1) {
    unsigned vp = 0, vq = 0;
    if (j >= off) { vp = sp[j-off]; vq = sq[j-off]; }
    __syncthreads();
    sp[j] += vp; sq[j] += vq;
    __syncthreads();
  }
  float A  = (float)(sp[j] - p);    // positives strictly above my e-bin
  float Bn = (float)(sq[j] - qe);   // negatives strictly above my e-bin
  float val = (t + 0.5f) * (2.0f/NB);
  float pf = (float)p, qf = (float)qe;
  float Jb = (A + Bn) / (G + Bn);
  float Ja = (A + Bn + pf + qf) / (G + Bn + qf);
  float contrib = val * (Ja - Jb);
  #pragma unroll
  for (int o = 32; o > 0; o >>= 1) contrib += __shfl_down(contrib, o);
  if ((t & 63) == 0) red[t >> 6] = contrib;
  __syncthreads();
  if (t == 0) {
    float tot = 0.0f;
    for (int i = 0; i < 16; ++i) tot += red[i];
    atomicAdd(&accd[(size_t)b*ACC_STRIDE + 82], (double)tot);
  }
}

// ---------- tier3 fallback: proven round-1 kernel (recompute path, SHIFT=18) ----------
__global__ __launch_bounds__(1024) void k_lov_old(const float* __restrict__ pred,
    const int* __restrict__ inst, const int* __restrict__ lab,
    const float* __restrict__ pairinfo, double* __restrict__ accd)
{
  constexpr int SHIFT = 18;
  constexpr int NBB = (0x40000000 >> SHIFT) + 1;
  extern __shared__ unsigned char smem[];
  unsigned* histP = reinterpret_cast<unsigned*>(smem);
  unsigned* histQ = histP + NBB;
  unsigned* scanP = histQ + NBB;
  unsigned* scanQ = scanP + 1024;
  float* red  = reinterpret_cast<float*>(scanQ + 1024);
  float* redf = red + 16;
  int t = threadIdx.x, bid = blockIdx.x;
  int b = bid >> 4, k = bid & 15;
  float4 pi = reinterpret_cast<const float4*>(pairinfo)[bid];
  float cx = pi.x, cy = pi.y, sexp = pi.z, G = pi.w;
  if (G <= 0.0f) return;
  for (int i = t; i < 2*NBB; i += 1024) histP[i] = 0u;
  __syncthreads();
  size_t ib = (size_t)b * HWPX;
  const float* pb = pred + (size_t)b * 4 * HWPX;
  const int target = k + 1;
  float fit = 0.0f;
  for (int j = 0; j < HWPX/1024; ++j) {
    int px = (j << 10) + t;
    int h = px >> 9, w = px & 511;
    float ex = tanhf(pb[px]) + w*(1.0f/1023.0f);
    float ey = tanhf(pb[HWPX+px]) + h*(1.0f/1023.0f);
    float sd = 1.0f/(1.0f + __expf(-pb[3*HWPX+px]));
    int lv = lab[ib+px], iv = inst[ib+px];
    float dx = ex - cx, dy = ey - cy;
    float d = __expf(-sexp * (dx*dx + dy*dy));
    bool m = (lv == 1) && (iv == target);
    float e = m ? fmaf(-2.0f, d, 2.0f) : 2.0f * d;
    unsigned key = __float_as_uint(e) >> SHIFT;
    atomicAdd(m ? &histP[key] : &histQ[key], 1u);
    if (m) { float df = sd - d; fit += df*df; }
  }
  #pragma unroll
  for (int o = 32; o > 0; o >>= 1) fit += __shfl_down(fit, o);
  if ((t & 63) == 0) redf[t >> 6] = fit;
  __syncthreads();
  constexpr int CB = NBB / 1024;
  int start = (NBB - 1) - t * CB;
  int nk = (t == 1023) ? (CB + 1) : CB;
  unsigned lp = 0, lq = 0;
  for (int i = 0; i < nk; ++i) { lp += histP[start-i]; lq += histQ[start-i]; }
  scanP[t] = lp; scanQ[t] = lq;
  __syncthreads();
  for (int off = 1; off < 1024; off <<= 1) {
    unsigned vp = 0, vq = 0;
    if (t >= off) { vp = scanP[t-off]; vq = scanQ[t-off]; }
    __syncthreads();
    scanP[t] += vp; scanQ[t] += vq;
    __syncthreads();
  }
  float A  = (float)(scanP[t] - lp);
  float Bn = (float)(scanQ[t] - lq);
  float contrib = 0.0f;
  for (int i = 0; i < nk; ++i) {
    int kk = start - i;
    unsigned p = histP[kk], q = histQ[kk];
    if (p | q) {
      float lo = __uint_as_float((unsigned)kk << SHIFT);
      float hi = __uint_as_float((unsigned)(kk+1) << SHIFT);
      float valv = 0.5f*(lo+hi);
      if (valv > 2.0f) valv = 2.0f;
      float pq = (float)(p + q), qf = (float)q;
      float Jb = (A + Bn) / (G + Bn);
      float Ja = (A + Bn + pq) / (G + Bn + qf);
      contrib += valv * (Ja - Jb);
      A += (float)p; Bn += qf;
    }
  }
  #pragma unroll
  for (int o = 32; o > 0; o >>= 1) contrib += __shfl_down(contrib, o);
  if ((t & 63) == 0) red[t >> 6] = contrib;
  __syncthreads();
  if (t == 0) {
    float tot = 0.0f, ft = 0.0f;
    for (int i = 0; i < 16; ++i) { tot += red[i]; ft += redf[i]; }
    atomicAdd(&accd[(size_t)b*ACC_STRIDE + 82], (double)tot);
    atomicAdd(&accd[(size_t)b*ACC_STRIDE + 81], (double)ft);
  }
}

__global__ void k_final(const double* __restrict__ accd, float* __restrict__ out)
{
  int t = threadIdx.x;
  double lb = 0.0;
  if (t < NIMG) {
    const double* ab = accd + (size_t)t*ACC_STRIDE;
    lb = (ab[82] + 10.0*ab[83]) / ab[84] + (ab[80] + ab[81]) * (1.0/(double)HWPX);
  }
  #pragma unroll
  for (int o = 4; o > 0; o >>= 1) lb += __shfl_down(lb, o);
  if (t == 0) out[0] = (float)(lb * 0.125);
}

extern "C" void kernel_launch(void* const* d_in, const int* in_sizes, int n_in,
                              void* d_out, int out_size, void* d_ws, size_t ws_size,
                              hipStream_t stream)
{
  const float* pred = (const float*)d_in[0];
  const int*   inst = (const int*)d_in[1];
  const int*   lab  = (const int*)d_in[2];
  float* out = (float*)d_out;

  size_t recB  = (size_t)NIMG * HWPX * sizeof(u64);         // 16.78 MB
  size_t partB = (size_t)NIMG * NGRP * NSPLIT * 8 * NB * 4; // 16.78 MB
  size_t accB  = (size_t)NIMG * ACC_STRIDE * sizeof(double);
  size_t pairB = 128 * 4 * sizeof(float);
  bool full = ws_size >= recB + partB + accB + pairB;

  char* ws = (char*)d_ws;
  if (full) {
    u64*      rec   = (u64*)ws;
    unsigned* part  = (unsigned*)(ws + recB);
    double*   accd  = (double*)(ws + recB + partB);
    float*    pairinfo = (float*)(ws + recB + partB + accB);
    hipMemsetAsync(accd, 0, accB, stream);
    k_prep<true><<<1024,256,0,stream>>>(pred, inst, lab, rec, accd);
    k_fin<<<1,128,0,stream>>>(accd, pairinfo);
    k_hist<<<NIMG*NGRP*NSPLIT,1024,0,stream>>>(rec, pairinfo, part, accd);
    k_scan<<<128,1024,0,stream>>>(part, pairinfo, accd);
    k_final<<<1,64,0,stream>>>(accd, out);
  } else {
    double* accd = (double*)ws;
    float* pairinfo = (float*)(accd + NIMG*ACC_STRIDE);
    hipMemsetAsync(accd, 0, accB, stream);
    k_prep<false><<<1024,256,0,stream>>>(pred, inst, lab, nullptr, accd);
    k_fin<<<1,128,0,stream>>>(accd, pairinfo);
    size_t lds18 = ((size_t)2*4097 + 2048)*4 + 128;
    k_lov_old<<<128,1024,lds18,stream>>>(pred, inst, lab, pairinfo, accd);
    k_final<<<1,64,0,stream>>>(accd, out);
  }
}